// Round 7
// baseline (383.117 us; speedup 1.0000x reference)
//
#include <hip/hip_runtime.h>
#include <hip/hip_bf16.h>

#define GD 64
#define GC 256

typedef unsigned short u16;
typedef unsigned int u32;
typedef short bf16x8 __attribute__((ext_vector_type(8)));
typedef float f32x4 __attribute__((ext_vector_type(4)));
typedef unsigned int u32x4 __attribute__((ext_vector_type(4)));

__device__ __forceinline__ u16 f2bf_rne(float f) {
    u32 u = __builtin_bit_cast(u32, f);
    u = (u + 0x7FFFu + ((u >> 16) & 1u)) >> 16;
    return (u16)u;
}

// round bits of f32 to the exact bf16-representable value (RNE)
__device__ __forceinline__ float bfval_u(u32 u) {
    u = (u + 0x7FFFu + ((u >> 16) & 1u)) & 0xFFFF0000u;
    return __builtin_bit_cast(float, u);
}

// ---- asm load primitives: volatile asm keeps issue order; compiler cannot
// ---- pair them with consumers. Consume only after vm_drain().
__device__ __forceinline__ u32x4 gload16(const void* p) {
    u32x4 d;
    asm volatile("global_load_dwordx4 %0, %1, off"
                 : "=&v"(d) : "v"((unsigned long long)(uintptr_t)p));
    return d;
}
__device__ __forceinline__ u32 gload4(const void* p) {
    u32 d;
    asm volatile("global_load_dword %0, %1, off"
                 : "=&v"(d) : "v"((unsigned long long)(uintptr_t)p));
    return d;
}
__device__ __forceinline__ void vm_drain() {
    asm volatile("s_waitcnt vmcnt(0)" ::: "memory");
    __builtin_amdgcn_sched_barrier(0);   // nothing crosses this (rule #18)
}

// ---------------------------------------------------------------- init/build map
// Also bakes the -inf dummy rows used for boundary/empty address-selects.
__global__ __launch_bounds__(256) void init_map(uint4* __restrict__ m,
        uint4* __restrict__ dF, uint4* __restrict__ dB) {
    int i = blockIdx.x * 256 + threadIdx.x;        // 65536 uint4 = 1 MB
    uint4 v;
    v.x = v.y = v.z = v.w = 0xFFFFFFFFu;
    m[i] = v;
    if (blockIdx.x == 0) {
        if (threadIdx.x < 64) {                    // 256 f32 of -inf (1 KB)
            uint4 f; f.x = f.y = f.z = f.w = 0xFF800000u;
            dF[threadIdx.x] = f;
        } else if (threadIdx.x < 96) {             // 256 bf16 of -inf (512 B)
            uint4 g; g.x = g.y = g.z = g.w = 0xFF80FF80u;
            dB[threadIdx.x - 64] = g;
        }
    }
}

__global__ __launch_bounds__(256) void build_map(const int* __restrict__ coords,
        int* __restrict__ map, int n) {
    int i = blockIdx.x * 256 + threadIdx.x;
    if (i < n) {
        int ix = coords[3 * i], iy = coords[3 * i + 1], iz = coords[3 * i + 2];
        map[(ix * GD + iy) * GD + iz] = i;         // coords unique (permutation)
    }
}

// 4 outputs (window 7, 10 inputs v[0..9]) via shared pair maxes.
__device__ __forceinline__ void max4pack(const float (&v)[10][8], u32 (&q)[4][4]) {
#pragma unroll
    for (int i = 0; i < 4; i++) {
        u32 h[4][2];
#pragma unroll
        for (int hh = 0; hh < 2; hh++) {
            int ch = 2 * i + hh;
            float p0 = fmaxf(v[0][ch], v[1][ch]);
            float p2 = fmaxf(v[2][ch], v[3][ch]);
            float p4 = fmaxf(v[4][ch], v[5][ch]);
            float p6 = fmaxf(v[6][ch], v[7][ch]);
            float p8 = fmaxf(v[8][ch], v[9][ch]);
            float o0 = fmaxf(fmaxf(p0, p2), fmaxf(p4, v[6][ch]));        // v0..v6
            float o1 = fmaxf(fmaxf(v[1][ch], p2), fmaxf(p4, p6));        // v1..v7
            float o2 = fmaxf(fmaxf(p2, p4), fmaxf(p6, v[8][ch]));        // v2..v8
            float o3 = fmaxf(fmaxf(v[3][ch], p4), fmaxf(p6, p8));        // v3..v9
            h[0][hh] = __builtin_bit_cast(u32, o0);
            h[1][hh] = __builtin_bit_cast(u32, o1);
            h[2][hh] = __builtin_bit_cast(u32, o2);
            h[3][hh] = __builtin_bit_cast(u32, o3);
        }
#pragma unroll
        for (int d = 0; d < 4; d++)
            q[d][i] = (h[d][0] >> 16) | (h[d][1] & 0xFFFF0000u);
    }
}

// ---------------------------------------------------------------- z pool (gather)
// Batch 1: 10 map loads (asm) -> drain. Batch 2: 20 feats loads (asm, dummy
// -inf row when cell empty / out of range) -> drain. Then pure VALU.
__global__ __launch_bounds__(256, 2) void pool_z_gather(const float* __restrict__ feats,
        const int* __restrict__ map, u16* __restrict__ grid,
        const float* __restrict__ dummyF) {
    int lane = threadIdx.x & 31;
    int gid = blockIdx.x * 8 + (threadIdx.x >> 5);   // 0..65535
    int L = gid >> 4;                                 // line = x*64+y
    int a0 = (gid & 15) << 2;                         // first output z
    const int* mrow = map + L * GD;
    u16* po = grid + ((size_t)L * GD + a0) * GC + lane * 8;

    u32 mr[10];
#pragma unroll
    for (int i = 0; i < 10; i++) {
        int wc = min(max(a0 - 3 + i, 0), 63);
        mr[i] = gload4(mrow + wc);
    }
    vm_drain();

    u32x4 ra[10], rb[10];
#pragma unroll
    for (int i = 0; i < 10; i++) {
        int w = a0 - 3 + i;
        int mi = (int)mr[i];
        bool live = ((unsigned)w < 64u) && (mi >= 0);
        const float* src = live ? (feats + (size_t)mi * GC + lane * 8)
                                : (dummyF + lane * 8);
        ra[i] = gload16(src);
        rb[i] = gload16(src + 4);
    }
    vm_drain();

    float v[10][8];
#pragma unroll
    for (int i = 0; i < 10; i++) {
#pragma unroll
        for (int c = 0; c < 4; c++) {
            v[i][c]     = bfval_u(ra[i][c]);
            v[i][4 + c] = bfval_u(rb[i][c]);
        }
    }

    u32 q[4][4];
    max4pack(v, q);
#pragma unroll
    for (int d = 0; d < 4; d++)                       // 4 contiguous 512-B stores
        *(uint4*)(po + (size_t)d * GC) = make_uint4(q[d][0], q[d][1], q[d][2], q[d][3]);
}

// ---------------------------------------------------------------- y pool (dense)
__global__ __launch_bounds__(256, 4) void pool_y(const u16* __restrict__ gin,
        u16* __restrict__ gout, const u16* __restrict__ dummyB) {
    int lane = threadIdx.x & 31;
    int gid = blockIdx.x * 8 + (threadIdx.x >> 5);   // 0..65535
    int L = gid >> 4;                                 // line = x*64+z
    int a0 = (gid & 15) << 2;                         // first output y
    int x = L >> 6, z = L & 63;
    size_t base = ((size_t)x * GD * GD + z) * GC + lane * 8;
    const size_t st = (size_t)GD * GC;                // +1 in y
    const u16* pin = gin + base;
    u16* po = gout + base + (size_t)a0 * st;
    const u16* dmy = dummyB + lane * 8;

    u32x4 c[10];
#pragma unroll
    for (int i = 0; i < 10; i++) {
        int w = a0 - 3 + i;
        const u16* src = ((unsigned)w < 64u) ? (pin + (size_t)w * st) : dmy;
        c[i] = gload16(src);
    }
    vm_drain();

    float v[10][8];
#pragma unroll
    for (int i = 0; i < 10; i++) {
#pragma unroll
        for (int k = 0; k < 4; k++) {
            v[i][2 * k]     = __builtin_bit_cast(float, c[i][k] << 16);
            v[i][2 * k + 1] = __builtin_bit_cast(float, c[i][k] & 0xFFFF0000u);
        }
    }

    u32 q[4][4];
    max4pack(v, q);
#pragma unroll
    for (int d = 0; d < 4; d++)
        *(uint4*)(po + (size_t)d * st) = make_uint4(q[d][0], q[d][1], q[d][2], q[d][3]);
}

// ---------------------------------------------------------------- x pool + compact
__global__ __launch_bounds__(256, 4) void pool_x_compact(const u16* __restrict__ gin,
        const int* __restrict__ map, u16* __restrict__ P,
        const u16* __restrict__ dummyB) {
    int lane = threadIdx.x & 31;
    int gid = blockIdx.x * 8 + (threadIdx.x >> 5);   // 0..65535
    int L = gid >> 4;                                 // line = y*64+z
    int a0 = (gid & 15) << 2;                         // first output x
    size_t base = (size_t)L * GC + lane * 8;
    const size_t st = (size_t)GD * GD * GC;           // +1 in x
    const u16* pin = gin + base;
    const u16* dmy = dummyB + lane * 8;

    u32 mo[4];
#pragma unroll
    for (int d = 0; d < 4; d++)                       // gating map entries (asm batch)
        mo[d] = gload4(map + (size_t)(a0 + d) * GD * GD + L);

    u32x4 c[10];
#pragma unroll
    for (int i = 0; i < 10; i++) {
        int w = a0 - 3 + i;
        const u16* src = ((unsigned)w < 64u) ? (pin + (size_t)w * st) : dmy;
        c[i] = gload16(src);
    }
    vm_drain();

    float v[10][8];
#pragma unroll
    for (int i = 0; i < 10; i++) {
#pragma unroll
        for (int k = 0; k < 4; k++) {
            v[i][2 * k]     = __builtin_bit_cast(float, c[i][k] << 16);
            v[i][2 * k + 1] = __builtin_bit_cast(float, c[i][k] & 0xFFFF0000u);
        }
    }

    u32 q[4][4];
    max4pack(v, q);
#pragma unroll
    for (int d = 0; d < 4; d++) {
        int mi = (int)mo[d];
        if (mi >= 0)
            *(uint4*)(P + (size_t)mi * GC + lane * 8) =
                make_uint4(q[d][0], q[d][1], q[d][2], q[d][3]);
    }
}

// ---------------------------------------------------------------- weight prep
__global__ __launch_bounds__(256) void prep_weights(const float* __restrict__ W1,
        const float* __restrict__ W2, u16* __restrict__ img1, u16* __restrict__ img2) {
    int t = blockIdx.x * 256 + threadIdx.x;   // 0..65535
    if (t < 32768) {
        int h = t >> 14, nn = (t >> 8) & 63, chunk = (t >> 3) & 31, j = t & 7;
        int k = chunk * 8 + j;
        img1[(h << 14) + nn * 256 + (((chunk ^ (nn & 7)) << 3) | j)] =
            f2bf_rne(W1[k * 128 + h * 64 + nn]);
    } else {
        int t2 = t - 32768;
        int h = t2 >> 14, nn = (t2 >> 7) & 127, chunk = (t2 >> 3) & 15, j = t2 & 7;
        int k = chunk * 8 + j;
        img2[(h << 14) + nn * 128 + (((chunk ^ (nn & 7)) << 3) | j)] =
            f2bf_rne(W2[k * 256 + h * 128 + nn]);
    }
}

// ---------------------------------------------------------------- GEMM1 (half-N)
__global__ __launch_bounds__(256, 4) void gemm1_kernel(const u16* __restrict__ P,
        const u16* __restrict__ img1, u16* __restrict__ H, int n, int nrb) {
    __shared__ __align__(16) u16 w1t[64 * 256];   // 32768 B; reused as hbuf
    int h = blockIdx.x >= nrb;
    int rb = blockIdx.x - (h ? nrb : 0);
    int tid = threadIdx.x;

    const uint4* src = (const uint4*)(img1 + (h << 14));
    uint4* dst = (uint4*)w1t;
#pragma unroll
    for (int i = 0; i < 8; i++) dst[i * 256 + tid] = src[i * 256 + tid];

    int wave = tid >> 6, lane = tid & 63, m16 = lane & 15, quad = lane >> 4;
    int row_a = rb * 64 + wave * 16 + m16;
    int ra = min(row_a, n - 1);
    const u16* yrow = P + (size_t)ra * GC;
    bf16x8 afr[8];
#pragma unroll
    for (int kk = 0; kk < 8; kk++)
        afr[kk] = *(const bf16x8*)(yrow + kk * 32 + quad * 8);
    __syncthreads();

    f32x4 acc[4];
#pragma unroll
    for (int t = 0; t < 4; t++) acc[t] = (f32x4){0.f, 0.f, 0.f, 0.f};
#pragma unroll
    for (int kk = 0; kk < 8; kk++) {
        int chunk = kk * 4 + quad;
#pragma unroll
        for (int t = 0; t < 4; t++) {
            int r = t * 16 + m16;
            bf16x8 b = *(const bf16x8*)&w1t[r * 256 + ((chunk ^ (r & 7)) << 3)];
            acc[t] = __builtin_amdgcn_mfma_f32_16x16x32_bf16(afr[kk], b, acc[t], 0, 0, 0);
        }
    }
    __syncthreads();   // w1t dead; reuse as hbuf

    u16* hbuf = w1t;
#pragma unroll
    for (int t = 0; t < 4; t++) {
        int col = t * 16 + m16;
        int c8 = col >> 3, j = col & 7;
#pragma unroll
        for (int rr = 0; rr < 4; rr++) {
            int row_l = wave * 16 + quad * 4 + rr;
            float hv = fmaxf(acc[t][rr], 0.0f);
            hbuf[row_l * 64 + (((c8 ^ (row_l & 7)) << 3) | j)] = f2bf_rne(hv);
        }
    }
    __syncthreads();
#pragma unroll
    for (int i = 0; i < 2; i++) {
        int cid = i * 256 + tid;            // 0..511 chunks of 8
        int row_l = cid >> 3, c8 = cid & 7;
        int grow = rb * 64 + row_l;
        if (grow < n) {
            bf16x8 v = *(const bf16x8*)&hbuf[row_l * 64 + ((c8 ^ (row_l & 7)) << 3)];
            *(bf16x8*)&H[(size_t)grow * 128 + h * 64 + c8 * 8] = v;
        }
    }
}

// ---------------------------------------------------------------- GEMM2 (half-N)
__global__ __launch_bounds__(256, 4) void gemm2_kernel(const u16* __restrict__ H,
        const u16* __restrict__ img2, const float* __restrict__ feats,
        float* __restrict__ out, int n, int nrb) {
    __shared__ __align__(16) char smem[64 * 140 * 4];   // 35840 B
    u16* w2t = (u16*)smem;
    float* zbuf = (float*)smem;
    int h = blockIdx.x >= nrb;
    int rb = blockIdx.x - (h ? nrb : 0);
    int tid = threadIdx.x;

    const uint4* src = (const uint4*)(img2 + (h << 14));
    uint4* dst = (uint4*)w2t;
#pragma unroll
    for (int i = 0; i < 8; i++) dst[i * 256 + tid] = src[i * 256 + tid];

    int wave = tid >> 6, lane = tid & 63, m16 = lane & 15, quad = lane >> 4;
    int row_a = rb * 64 + wave * 16 + m16;
    int ra = min(row_a, n - 1);
    const u16* hrow = H + (size_t)ra * 128;
    bf16x8 afr[4];
#pragma unroll
    for (int kk = 0; kk < 4; kk++)
        afr[kk] = *(const bf16x8*)(hrow + kk * 32 + quad * 8);
    __syncthreads();

    f32x4 acc[8];
#pragma unroll
    for (int t = 0; t < 8; t++) acc[t] = (f32x4){0.f, 0.f, 0.f, 0.f};
#pragma unroll
    for (int kk = 0; kk < 4; kk++) {
        int chunk = kk * 4 + quad;
#pragma unroll
        for (int t = 0; t < 8; t++) {
            int nn = t * 16 + m16;
            bf16x8 b = *(const bf16x8*)&w2t[nn * 128 + ((chunk ^ (nn & 7)) << 3)];
            acc[t] = __builtin_amdgcn_mfma_f32_16x16x32_bf16(afr[kk], b, acc[t], 0, 0, 0);
        }
    }
    __syncthreads();   // w2t dead; write logits into zbuf

#pragma unroll
    for (int t = 0; t < 8; t++) {
        int col = t * 16 + m16;
#pragma unroll
        for (int rr = 0; rr < 4; rr++) {
            int row_l = wave * 16 + quad * 4 + rr;
            zbuf[row_l * 140 + col] = acc[t][rr];
        }
    }
    __syncthreads();
#pragma unroll
    for (int i = 0; i < 8; i++) {
        int f = i * 256 + tid;              // 0..2047 float4s
        int row_l = f >> 5, c4 = f & 31;
        int grow = rb * 64 + row_l;
        if (grow < n) {
            f32x4 z = *(const f32x4*)&zbuf[row_l * 140 + c4 * 4];
            size_t o = (size_t)grow * 256 + h * 128 + c4 * 4;
            f32x4 ft = *(const f32x4*)&feats[o];
            f32x4 r;
#pragma unroll
            for (int c = 0; c < 4; c++)
                r[c] = ft[c] / (1.0f + __expf(-z[c]));
            *(f32x4*)&out[o] = r;
        }
    }
}

// ---------------------------------------------------------------- launch
extern "C" void kernel_launch(void* const* d_in, const int* in_sizes, int n_in,
                              void* d_out, int out_size, void* d_ws, size_t ws_size,
                              hipStream_t stream) {
    const float* feats = (const float*)d_in[0];
    const int* coords = (const int*)d_in[1];
    const float* W1 = (const float*)d_in[2];
    const float* W2 = (const float*)d_in[3];
    float* out = (float*)d_out;

    int n = in_sizes[1] / 3;                       // 100000 points

    size_t grid_bytes = (size_t)GD * GD * GD * GC * 2;          // 134,217,728
    size_t P_bytes = (size_t)n * GC * 2;                        //  51,200,000
    size_t H_bytes = (size_t)n * 128 * 2;                       //  25,600,000
    u16* grid = (u16*)d_ws;                                     // never initialized
    u16* grid2 = (u16*)((char*)d_ws + grid_bytes);              // y-pass output
    u16* P = (u16*)((char*)d_ws + 2 * grid_bytes);
    u16* H = (u16*)((char*)d_ws + 2 * grid_bytes + P_bytes);
    int* map = (int*)((char*)d_ws + 2 * grid_bytes + P_bytes + H_bytes);
    u16* img1 = (u16*)((char*)map + (size_t)GD * GD * GD * 4);  // +1 MB
    u16* img2 = img1 + 32768;
    float* dummyF = (float*)(img2 + 32768);        // 256 f32 -inf (1 KB)
    u16* dummyB = (u16*)(dummyF + 256);            // 256 bf16 -inf (512 B)

    init_map<<<256, 256, 0, stream>>>((uint4*)map, (uint4*)dummyF, (uint4*)dummyB);
    prep_weights<<<256, 256, 0, stream>>>(W1, W2, img1, img2);
    build_map<<<(n + 255) / 256, 256, 0, stream>>>(coords, map, n);

    pool_z_gather<<<8192, 256, 0, stream>>>(feats, map, grid, dummyF);    // z
    pool_y<<<8192, 256, 0, stream>>>(grid, grid2, dummyB);                // y
    pool_x_compact<<<8192, 256, 0, stream>>>(grid2, map, P, dummyB);      // x -> compact

    int nrb = (n + 63) / 64;
    gemm1_kernel<<<2 * nrb, 256, 0, stream>>>(P, img1, H, n, nrb);
    gemm2_kernel<<<2 * nrb, 256, 0, stream>>>(H, img2, feats, out, n, nrb);
}